// Round 5
// baseline (790.922 us; speedup 1.0000x reference)
//
#include <hip/hip_runtime.h>

// Attention_2035814498461 on MI355X (gfx950).  [Round-4 resubmit: bench died
// with infra-level "container failed twice" before executing (same error that
// hit Round 2, whose identical source then PASSED in Round 3). Source
// re-audited: store alignment, bounds, no hang vectors, graph-capture-safe.]
// B=2 N=2048 C=1024 H=16 hd=64, causal mask, outputs (x fp32, attn fp32).
// bf16 MFMA everywhere; two-pass attention (recompute QK^T, l first).
// vs 715us:
//  - gemm_qkv mode-2 (Vt) store: was 64 scalar 2B stores/thread at 4KB stride
//    (~32x write amplification); now u16x4 stores, 4-lane groups 32B-contiguous.
//  - attn: BARRIER-FREE rewrite. No LDS staging of Q/K/V at all: fragments
//    loaded directly from global (K/V are L2-resident: 16MB). Every fragment
//    load is 64B-contiguous per instruction. Waves fully independent -> no
//    vmcnt(0) barrier drains, 8 free-running waves/CU hide L2 latency.
//    Only LDS left: per-wave fp32 P tile (lgkmcnt-ordered, no syncthreads).
//  - causal pairing (p, 31-p) kept: uniform 33 chunk-iters/block.

typedef unsigned short u16;
typedef unsigned int u32;
typedef __attribute__((ext_vector_type(8))) short s16x8;
typedef __attribute__((ext_vector_type(4))) float f32x4;
typedef __attribute__((ext_vector_type(4))) u16 u16x4;

#define AS1 __attribute__((address_space(1)))
#define AS3 __attribute__((address_space(3)))

static __device__ __forceinline__ u16 f2bf(float f) {
  u32 u = __builtin_bit_cast(u32, f);
  u = (u + 0x7fffu + ((u >> 16) & 1u)) >> 16;
  return (u16)u;
}

static __device__ __forceinline__ void gll16(const u16* g, u16* l) {
  // async global->LDS, 16B per lane; LDS dest must be wave-uniform base + lane*16
  __builtin_amdgcn_global_load_lds((const AS1 u32*)g, (AS3 u32*)l, 16, 0, 0);
}

static __device__ __forceinline__ f32x4 mfma_bf16(s16x8 a, s16x8 b, f32x4 c) {
  return __builtin_amdgcn_mfma_f32_16x16x32_bf16(a, b, c, 0, 0, 0);
}

// ---------------- merged cast fp32 -> bf16 ----------------
__global__ __launch_bounds__(256) void cast_all_kernel(
    const float* __restrict__ q, const float* __restrict__ k, const float* __restrict__ v,
    const float* __restrict__ qkv_w, const float* __restrict__ proj_w,
    u16* __restrict__ qb, u16* __restrict__ kb, u16* __restrict__ vb,
    u16* __restrict__ wb, u16* __restrict__ pwb) {
  int i = blockIdx.x * 256 + threadIdx.x;
  const float* src; u16* dst; int off;
  if (i < 1048576)       { src = q;      dst = qb;  off = i; }
  else if (i < 2097152)  { src = k;      dst = kb;  off = i - 1048576; }
  else if (i < 3145728)  { src = v;      dst = vb;  off = i - 2097152; }
  else if (i < 3932160)  { src = qkv_w;  dst = wb;  off = i - 3145728; }
  else if (i < 4194304)  { src = proj_w; dst = pwb; off = i - 3932160; }
  else return;
  f32x4 vv = ((const f32x4*)src)[off];
  u16x4 o = { f2bf(vv.x), f2bf(vv.y), f2bf(vv.z), f2bf(vv.w) };
  ((u16x4*)dst)[off] = o;
}

// ---------------- shared 128x128 BT-GEMM core, K=1024 (unchanged) ----------------
static __device__ __forceinline__ void gemm_core_1024(
    const u16* __restrict__ A, const u16* __restrict__ Bm,
    int m0, int n0, int t, u16* a_s, u16* b_s, f32x4 acc[4][4]) {
  const int lane = t & 63;
  const int w = t >> 6;
  const int wm = (w & 1) * 64, wn = (w >> 1) * 64;
  const int lrow = lane & 15, lq = lane >> 4;
  const int r0 = t >> 2;          // staging row 0..63
  const int c0 = (t & 3) * 8;     // staging col (elements)

  for (int kt = 0; kt < 1024; kt += 32) {
    __syncthreads();
    gll16(A  + (size_t)(m0 + r0)      * 1024 + kt + c0, &a_s[(size_t)t * 8]);
    gll16(A  + (size_t)(m0 + r0 + 64) * 1024 + kt + c0, &a_s[(size_t)(t + 256) * 8]);
    gll16(Bm + (size_t)(n0 + r0)      * 1024 + kt + c0, &b_s[(size_t)t * 8]);
    gll16(Bm + (size_t)(n0 + r0 + 64) * 1024 + kt + c0, &b_s[(size_t)(t + 256) * 8]);
    __syncthreads();
    s16x8 af[4], bfr[4];
#pragma unroll
    for (int x = 0; x < 4; x++) af[x]  = *(const s16x8*)&a_s[(wm + x*16 + lrow)*32 + lq*8];
#pragma unroll
    for (int x = 0; x < 4; x++) bfr[x] = *(const s16x8*)&b_s[(wn + x*16 + lrow)*32 + lq*8];
#pragma unroll
    for (int tm = 0; tm < 4; tm++)
#pragma unroll
      for (int tn = 0; tn < 4; tn++)
        acc[tm][tn] = mfma_bf16(af[tm], bfr[tn], acc[tm][tn]);
  }
}

// ---------------- QKV projection ----------------
__global__ __launch_bounds__(256) void gemm_qkv_kernel(
    const u16* __restrict__ qb, const u16* __restrict__ kb, const u16* __restrict__ vb,
    const u16* __restrict__ wb, u16* __restrict__ Qh, u16* __restrict__ Kh,
    u16* __restrict__ Vt) {
  __shared__ u16 a_s[128*32], b_s[128*32];
  const int mode = blockIdx.z;
  const u16* A = (mode == 0) ? qb : (mode == 1) ? kb : vb;
  const u16* Bm = wb + (size_t)mode * (1024 * 1024);
  const int m0 = blockIdx.y * 128, n0 = blockIdx.x * 128;
  const int t = threadIdx.x;
  f32x4 acc[4][4];
  const f32x4 Z = {0.f, 0.f, 0.f, 0.f};
#pragma unroll
  for (int i = 0; i < 4; i++)
#pragma unroll
    for (int j = 0; j < 4; j++) acc[i][j] = Z;

  gemm_core_1024(A, Bm, m0, n0, t, a_s, b_s, acc);

  const int lane = t & 63, w = t >> 6;
  const int wm = (w & 1) * 64, wn = (w >> 1) * 64;
  const int lrow = lane & 15, lq = lane >> 4;
#pragma unroll
  for (int tm = 0; tm < 4; tm++) {
#pragma unroll
    for (int tn = 0; tn < 4; tn++) {
      const int ng = n0 + wn + tn * 16 + lrow;
      const int h = ng >> 6, d = ng & 63;
      if (mode == 2) {
        // Vt[d][s]: each lane owns 4 consecutive s at fixed d -> one u16x4
        // (8B) store; 4-lane lq-groups form 32B-contiguous segments.
        const int mg = m0 + wm + tm * 16 + lq * 4;
        const int b = mg >> 11, s = mg & 2047;
        u16x4 o = { f2bf(acc[tm][tn][0]), f2bf(acc[tm][tn][1]),
                    f2bf(acc[tm][tn][2]), f2bf(acc[tm][tn][3]) };
        *(u16x4*)&Vt[((size_t)(b * 16 + h) * 64 + d) * 2048 + s] = o;
      } else {
#pragma unroll
        for (int i = 0; i < 4; i++) {
          const int mg = m0 + wm + tm * 16 + lq * 4 + i;
          const int b = mg >> 11, s = mg & 2047;
          const float v = acc[tm][tn][i];
          if (mode == 0)
            Qh[((size_t)(b * 16 + h) * 2048 + s) * 64 + d] = f2bf(v * 0.125f);
          else
            Kh[((size_t)(b * 16 + h) * 2048 + s) * 64 + d] = f2bf(v);
        }
      }
    }
  }
}

// ---------------- output projection (unchanged) ----------------
__global__ __launch_bounds__(256) void gemm_proj_kernel(
    const u16* __restrict__ xatt, const u16* __restrict__ pwb,
    const float* __restrict__ bias, float* __restrict__ out) {
  __shared__ u16 a_s[128*32], b_s[128*32];
  const int m0 = blockIdx.y * 128, n0 = blockIdx.x * 128;
  const int t = threadIdx.x;
  f32x4 acc[4][4];
  const f32x4 Z = {0.f, 0.f, 0.f, 0.f};
#pragma unroll
  for (int i = 0; i < 4; i++)
#pragma unroll
    for (int j = 0; j < 4; j++) acc[i][j] = Z;

  gemm_core_1024(xatt, pwb, m0, n0, t, a_s, b_s, acc);

  const int lane = t & 63, w = t >> 6;
  const int wm = (w & 1) * 64, wn = (w >> 1) * 64;
  const int lrow = lane & 15, lq = lane >> 4;
#pragma unroll
  for (int tn = 0; tn < 4; tn++) {
    const int ng = n0 + wn + tn * 16 + lrow;
    const float bv = bias[ng];
#pragma unroll
    for (int tm = 0; tm < 4; tm++) {
#pragma unroll
      for (int i = 0; i < 4; i++) {
        const int mg = m0 + wm + tm * 16 + lq * 4 + i;
        out[(size_t)mg * 1024 + ng] = acc[tm][tn][i] + bv;
      }
    }
  }
}

// ---------------- fused causal attention (barrier-free) ----------------
// Block = pair of q-tiles {p*64, (31-p)*64} x one bh; 4 independent waves,
// each owning 16 q-rows of both chunks. All fragments loaded directly from
// global (64B-contiguous per instruction; K/V are L2-resident). Zero
// __syncthreads. Per-wave fp32 P tile in LDS (in-wave lgkmcnt ordering only).

static __device__ __forceinline__ void qk_tile(const s16x8 qf[2], const s16x8 kf[4][2],
                                               f32x4 sacc[4]) {
  const f32x4 Z = {0.f, 0.f, 0.f, 0.f};
#pragma unroll
  for (int tn = 0; tn < 4; tn++) {
    sacc[tn] = Z;
#pragma unroll
    for (int kq = 0; kq < 2; kq++)
      sacc[tn] = mfma_bf16(qf[kq], kf[tn][kq], sacc[tn]);
  }
}

static __device__ __forceinline__ void expsum_tile(const f32x4 sacc[4], bool diag,
                                                   int lrow, int rbase, float l_acc[4]) {
  float part[4] = {0.f, 0.f, 0.f, 0.f};
#pragma unroll
  for (int tn = 0; tn < 4; tn++)
#pragma unroll
    for (int i = 0; i < 4; i++) {
      const bool ok = !diag || (tn * 16 + lrow <= rbase + i);
      part[i] += ok ? __expf(sacc[tn][i]) : 0.f;
    }
#pragma unroll
  for (int i = 0; i < 4; i++) {
    float s = part[i];
    s += __shfl_xor(s, 1, 16);
    s += __shfl_xor(s, 2, 16);
    s += __shfl_xor(s, 4, 16);
    s += __shfl_xor(s, 8, 16);
    l_acc[i] += s;
  }
}

// P phase: compute p, stage to per-wave fp32 LDS tile (stride 68), emit 4
// full-128B-line dwordx4 attn stores, rebuild pf via f2bf (bit-identical).
static __device__ __forceinline__ void p_phase(const f32x4 sacc[4], bool diag,
                                               int lane, int lrow, int lq, int w,
                                               const float invl[4], float* pw,
                                               float* __restrict__ gb, s16x8 pf[2]) {
#pragma unroll
  for (int tn = 0; tn < 4; tn++)
#pragma unroll
    for (int i = 0; i < 4; i++) {
      const int rl = lq * 4 + i;
      const bool ok = !diag || (tn * 16 + lrow <= w * 16 + rl);
      const float pv = ok ? __expf(sacc[tn][i]) * invl[i] : 0.f;
      pw[rl * 68 + tn * 16 + lrow] = pv;
    }
  const int rr = lane >> 3, c8 = (lane & 7) * 4;
#pragma unroll
  for (int j = 0; j < 2; j++)
#pragma unroll
    for (int m = 0; m < 2; m++) {
      f32x4 vv = *(const f32x4*)&pw[(rr + 8 * j) * 68 + m * 32 + c8];
      *(f32x4*)&gb[(size_t)(rr + 8 * j) * 2048 + m * 32 + c8] = vv;
    }
#pragma unroll
  for (int kq = 0; kq < 2; kq++) {
    f32x4 lo = *(const f32x4*)&pw[lrow * 68 + kq * 32 + lq * 8];
    f32x4 hi = *(const f32x4*)&pw[lrow * 68 + kq * 32 + lq * 8 + 4];
    s16x8 r;
    r[0] = (short)f2bf(lo.x); r[1] = (short)f2bf(lo.y);
    r[2] = (short)f2bf(lo.z); r[3] = (short)f2bf(lo.w);
    r[4] = (short)f2bf(hi.x); r[5] = (short)f2bf(hi.y);
    r[6] = (short)f2bf(hi.z); r[7] = (short)f2bf(hi.w);
    pf[kq] = r;
  }
}

__global__ __launch_bounds__(256, 2) void attn_kernel(
    const u16* __restrict__ Qh, const u16* __restrict__ Kh, const u16* __restrict__ Vt,
    float* __restrict__ attn, u16* __restrict__ xatt, const int* __restrict__ use_mask_p) {
  __shared__ float p32[4][16 * 68];   // per-wave fp32 P tile, 17.4 KB total

  const int bh = blockIdx.y;
  const int p  = blockIdx.x;            // pair index 0..15
  const int t = threadIdx.x;
  const int lane = t & 63, w = t >> 6;
  const int lrow = lane & 15, lq = lane >> 4;
  const int use_mask = *use_mask_p;

  const int q0[2] = { p * 64, (31 - p) * 64 };
  const int Tc[2] = { use_mask ? p : 31, use_mask ? 31 - p : 31 };
  const int Tmax  = Tc[1];              // >= Tc[0] always

  const u16* kg = Kh + (size_t)bh * (2048 * 64);
  const u16* vg = Vt + (size_t)bh * (64 * 2048);

  // Q fragments: direct global (16 rows x 128B, 64B/instr contiguous)
  s16x8 qf[2][2];
#pragma unroll
  for (int c = 0; c < 2; c++)
#pragma unroll
    for (int kq = 0; kq < 2; kq++)
      qf[c][kq] = *(const s16x8*)&Qh[((size_t)bh * 2048 + q0[c] + w * 16 + lrow) * 64
                                     + kq * 32 + lq * 8];

  const int rbase = w * 16 + lq * 4;

  // ---- pass 1: row sums l ----
  float l_acc[2][4];
#pragma unroll
  for (int c = 0; c < 2; c++)
#pragma unroll
    for (int i = 0; i < 4; i++) l_acc[c][i] = 0.f;

  for (int tt = 0; tt <= Tmax; tt++) {
    s16x8 kf[4][2];
#pragma unroll
    for (int tn = 0; tn < 4; tn++)
#pragma unroll
      for (int kq = 0; kq < 2; kq++)
        kf[tn][kq] = *(const s16x8*)&kg[(size_t)(tt * 64 + tn * 16 + lrow) * 64
                                        + kq * 32 + lq * 8];
    f32x4 sacc[4];
    __builtin_amdgcn_s_setprio(1);
    qk_tile(qf[1], kf, sacc);
    __builtin_amdgcn_s_setprio(0);
    expsum_tile(sacc, use_mask && (tt == Tc[1]), lrow, rbase, l_acc[1]);
    if (tt <= Tc[0]) {
      __builtin_amdgcn_s_setprio(1);
      qk_tile(qf[0], kf, sacc);
      __builtin_amdgcn_s_setprio(0);
      expsum_tile(sacc, use_mask && (tt == Tc[0]), lrow, rbase, l_acc[0]);
    }
  }

  float inv_l[2][4];
#pragma unroll
  for (int c = 0; c < 2; c++)
#pragma unroll
    for (int i = 0; i < 4; i++) inv_l[c][i] = 1.0f / l_acc[c][i];

  // ---- pass 2: P write + O = P@V ----
  f32x4 oacc[2][4];
  const f32x4 Z = {0.f, 0.f, 0.f, 0.f};
#pragma unroll
  for (int c = 0; c < 2; c++)
#pragma unroll
    for (int i = 0; i < 4; i++) oacc[c][i] = Z;

  float* pw = &p32[w][0];

  for (int tt = 0; tt <= Tmax; tt++) {
    // K and V fragments direct from global; vf used only at the end of the
    // iteration (issue-early / use-late hides L2 latency under QK + exp).
    s16x8 kf[4][2];
#pragma unroll
    for (int tn = 0; tn < 4; tn++)
#pragma unroll
      for (int kq = 0; kq < 2; kq++)
        kf[tn][kq] = *(const s16x8*)&kg[(size_t)(tt * 64 + tn * 16 + lrow) * 64
                                        + kq * 32 + lq * 8];
    s16x8 vf[4][2];
#pragma unroll
    for (int td = 0; td < 4; td++)
#pragma unroll
      for (int kq = 0; kq < 2; kq++)
        vf[td][kq] = *(const s16x8*)&vg[(size_t)(td * 16 + lrow) * 2048 + tt * 64
                                        + kq * 32 + lq * 8];

    const bool act0 = (tt <= Tc[0]);

    // ---- chunk 1 (always active) ----
    {
      f32x4 sacc[4];
      __builtin_amdgcn_s_setprio(1);
      qk_tile(qf[1], kf, sacc);
      __builtin_amdgcn_s_setprio(0);
      s16x8 pf[2];
      float* gb = attn + ((size_t)(bh * 2048 + q0[1] + w * 16)) * 2048 + tt * 64;
      p_phase(sacc, use_mask && (tt == Tc[1]), lane, lrow, lq, w, inv_l[1], pw, gb, pf);
      __builtin_amdgcn_s_setprio(1);
#pragma unroll
      for (int td = 0; td < 4; td++)
#pragma unroll
        for (int kq = 0; kq < 2; kq++)
          oacc[1][td] = mfma_bf16(pf[kq], vf[td][kq], oacc[1][td]);
      __builtin_amdgcn_s_setprio(0);
    }
    // ---- chunk 0 (active while tt <= Tc[0]) ----
    if (act0) {
      f32x4 sacc[4];
      __builtin_amdgcn_s_setprio(1);
      qk_tile(qf[0], kf, sacc);
      __builtin_amdgcn_s_setprio(0);
      s16x8 pf[2];
      float* gb = attn + ((size_t)(bh * 2048 + q0[0] + w * 16)) * 2048 + tt * 64;
      p_phase(sacc, use_mask && (tt == Tc[0]), lane, lrow, lq, w, inv_l[0], pw, gb, pf);
      __builtin_amdgcn_s_setprio(1);
#pragma unroll
      for (int td = 0; td < 4; td++)
#pragma unroll
        for (int kq = 0; kq < 2; kq++)
          oacc[0][td] = mfma_bf16(pf[kq], vf[td][kq], oacc[0][td]);
      __builtin_amdgcn_s_setprio(0);
    }
  }

  // ---- O -> xatt (B,N,C) bf16, both chunks ----
  const int b = bh >> 4, h = bh & 15;
#pragma unroll
  for (int c = 0; c < 2; c++)
#pragma unroll
    for (int td = 0; td < 4; td++)
#pragma unroll
      for (int i = 0; i < 4; i++) {
        const int row = q0[c] + w * 16 + lq * 4 + i;
        xatt[((size_t)(b * 2048 + row)) * 1024 + h * 64 + td * 16 + lrow] = f2bf(oacc[c][td][i]);
      }

  // ---- zero-fill masked upper region: full 128B lines (8 lanes x 16B / row) ----
  if (use_mask) {
    const f32x4 Z4 = {0.f, 0.f, 0.f, 0.f};
    const int rr = t >> 3;          // 0..31
    const int c8 = (t & 7) * 4;     // float offset within 32-float chunk
#pragma unroll
    for (int c = 0; c < 2; c++) {
      const int zc0 = q0[c] + 64;
      if (zc0 < 2048) {
        const int n32 = (2048 - zc0) >> 5;   // 32-float (128B) chunks per row
        float* zb = attn + ((size_t)bh * 2048 + q0[c]) * 2048 + zc0;
        for (int j = 0; j < n32; j++) {
          *(f32x4*)&zb[(size_t)rr * 2048 + j * 32 + c8] = Z4;
          *(f32x4*)&zb[(size_t)(rr + 32) * 2048 + j * 32 + c8] = Z4;
        }
      }
    }
  }
}

extern "C" void kernel_launch(void* const* d_in, const int* in_sizes, int n_in,
                              void* d_out, int out_size, void* d_ws, size_t ws_size,
                              hipStream_t stream) {
  const float* q      = (const float*)d_in[0];
  const float* k      = (const float*)d_in[1];
  const float* v      = (const float*)d_in[2];
  const float* qkv_w  = (const float*)d_in[3];
  const float* proj_w = (const float*)d_in[4];
  const float* proj_b = (const float*)d_in[5];
  const int*   use_mask = (const int*)d_in[6];

  const size_t MB = 1024 * 1024;
  char* ws = (char*)d_ws;
  u16* qb  = (u16*)(ws + 0 * MB);   // 8 MB (reused as xatt after QKV gemm)
  u16* kb  = (u16*)(ws + 8 * MB);   // 8 MB
  u16* vb  = (u16*)(ws + 16 * MB);  // 8 MB
  u16* wb  = (u16*)(ws + 24 * MB);  // 6 MB
  u16* pwb = (u16*)(ws + 30 * MB);  // 2 MB
  u16* Qh  = (u16*)(ws + 32 * MB);  // 8 MB
  u16* Kh  = (u16*)(ws + 40 * MB);  // 8 MB
  u16* Vt  = (u16*)(ws + 48 * MB);  // 8 MB
  u16* xat = qb;                    // qb dead after gemm_qkv; reuse

  float* out_x    = (float*)d_out;
  float* out_attn = out_x + (size_t)2 * 2048 * 1024;

  cast_all_kernel<<<16384, 256, 0, stream>>>(q, k, v, qkv_w, proj_w, qb, kb, vb, wb, pwb);

  gemm_qkv_kernel<<<dim3(8, 32, 3), 256, 0, stream>>>(qb, kb, vb, wb, Qh, Kh, Vt);
  attn_kernel<<<dim3(16, 32), 256, 0, stream>>>(Qh, Kh, Vt, out_attn, xat, use_mask);
  gemm_proj_kernel<<<dim3(8, 32), 256, 0, stream>>>(xat, pwb, proj_b, out_x);
}

// Round 6
// 724.533 us; speedup vs baseline: 1.0916x; 1.0916x over previous
//
#include <hip/hip_runtime.h>

// Attention_2035814498461 on MI355X (gfx950).
// B=2 N=2048 C=1024 H=16 hd=64, causal mask, outputs (x fp32, attn fp32).
// Round-6: EXACT Round-3 attn (LDS-staged, paired, dbuf, swizzled — proven
// 715us) + single isolated change: gemm_qkv Vt store as u16x4 (was 64 scalar
// 2B stores/thread, each touching 64 cache lines -> 16x L2 transaction
// pressure). Barrier-free attn of R5 REVERTED (regressed +75us: 2 waves/SIMD
// could not hide L2 latency without LDS staging).
// Accounting (R5 post-mortem): ~355us harness poison-fill sits inside the
// timed window; addressable kernel budget ~360us; structural floor ~545us.

typedef unsigned short u16;
typedef unsigned int u32;
typedef __attribute__((ext_vector_type(8))) short s16x8;
typedef __attribute__((ext_vector_type(4))) float f32x4;
typedef __attribute__((ext_vector_type(4))) u16 u16x4;

#define AS1 __attribute__((address_space(1)))
#define AS3 __attribute__((address_space(3)))

static __device__ __forceinline__ u16 f2bf(float f) {
  u32 u = __builtin_bit_cast(u32, f);
  u = (u + 0x7fffu + ((u >> 16) & 1u)) >> 16;
  return (u16)u;
}

static __device__ __forceinline__ void gll16(const u16* g, u16* l) {
  // async global->LDS, 16B per lane; LDS dest must be wave-uniform base + lane*16
  __builtin_amdgcn_global_load_lds((const AS1 u32*)g, (AS3 u32*)l, 16, 0, 0);
}

static __device__ __forceinline__ f32x4 mfma_bf16(s16x8 a, s16x8 b, f32x4 c) {
  return __builtin_amdgcn_mfma_f32_16x16x32_bf16(a, b, c, 0, 0, 0);
}

// ---------------- merged cast fp32 -> bf16 ----------------
__global__ __launch_bounds__(256) void cast_all_kernel(
    const float* __restrict__ q, const float* __restrict__ k, const float* __restrict__ v,
    const float* __restrict__ qkv_w, const float* __restrict__ proj_w,
    u16* __restrict__ qb, u16* __restrict__ kb, u16* __restrict__ vb,
    u16* __restrict__ wb, u16* __restrict__ pwb) {
  int i = blockIdx.x * 256 + threadIdx.x;
  const float* src; u16* dst; int off;
  if (i < 1048576)       { src = q;      dst = qb;  off = i; }
  else if (i < 2097152)  { src = k;      dst = kb;  off = i - 1048576; }
  else if (i < 3145728)  { src = v;      dst = vb;  off = i - 2097152; }
  else if (i < 3932160)  { src = qkv_w;  dst = wb;  off = i - 3145728; }
  else if (i < 4194304)  { src = proj_w; dst = pwb; off = i - 3932160; }
  else return;
  f32x4 vv = ((const f32x4*)src)[off];
  u16x4 o = { f2bf(vv.x), f2bf(vv.y), f2bf(vv.z), f2bf(vv.w) };
  ((u16x4*)dst)[off] = o;
}

// ---------------- shared 128x128 BT-GEMM core, K=1024 ----------------
static __device__ __forceinline__ void gemm_core_1024(
    const u16* __restrict__ A, const u16* __restrict__ Bm,
    int m0, int n0, int t, u16* a_s, u16* b_s, f32x4 acc[4][4]) {
  const int lane = t & 63;
  const int w = t >> 6;
  const int wm = (w & 1) * 64, wn = (w >> 1) * 64;
  const int lrow = lane & 15, lq = lane >> 4;
  const int r0 = t >> 2;          // staging row 0..63
  const int c0 = (t & 3) * 8;     // staging col (elements)

  for (int kt = 0; kt < 1024; kt += 32) {
    __syncthreads();
    gll16(A  + (size_t)(m0 + r0)      * 1024 + kt + c0, &a_s[(size_t)t * 8]);
    gll16(A  + (size_t)(m0 + r0 + 64) * 1024 + kt + c0, &a_s[(size_t)(t + 256) * 8]);
    gll16(Bm + (size_t)(n0 + r0)      * 1024 + kt + c0, &b_s[(size_t)t * 8]);
    gll16(Bm + (size_t)(n0 + r0 + 64) * 1024 + kt + c0, &b_s[(size_t)(t + 256) * 8]);
    __syncthreads();
    s16x8 af[4], bfr[4];
#pragma unroll
    for (int x = 0; x < 4; x++) af[x]  = *(const s16x8*)&a_s[(wm + x*16 + lrow)*32 + lq*8];
#pragma unroll
    for (int x = 0; x < 4; x++) bfr[x] = *(const s16x8*)&b_s[(wn + x*16 + lrow)*32 + lq*8];
#pragma unroll
    for (int tm = 0; tm < 4; tm++)
#pragma unroll
      for (int tn = 0; tn < 4; tn++)
        acc[tm][tn] = mfma_bf16(af[tm], bfr[tn], acc[tm][tn]);
  }
}

// ---------------- QKV projection (Vt store coalesced) ----------------
__global__ __launch_bounds__(256) void gemm_qkv_kernel(
    const u16* __restrict__ qb, const u16* __restrict__ kb, const u16* __restrict__ vb,
    const u16* __restrict__ wb, u16* __restrict__ Qh, u16* __restrict__ Kh,
    u16* __restrict__ Vt) {
  __shared__ u16 a_s[128*32], b_s[128*32];
  const int mode = blockIdx.z;
  const u16* A = (mode == 0) ? qb : (mode == 1) ? kb : vb;
  const u16* Bm = wb + (size_t)mode * (1024 * 1024);
  const int m0 = blockIdx.y * 128, n0 = blockIdx.x * 128;
  const int t = threadIdx.x;
  f32x4 acc[4][4];
  const f32x4 Z = {0.f, 0.f, 0.f, 0.f};
#pragma unroll
  for (int i = 0; i < 4; i++)
#pragma unroll
    for (int j = 0; j < 4; j++) acc[i][j] = Z;

  gemm_core_1024(A, Bm, m0, n0, t, a_s, b_s, acc);

  const int lane = t & 63, w = t >> 6;
  const int wm = (w & 1) * 64, wn = (w >> 1) * 64;
  const int lrow = lane & 15, lq = lane >> 4;
#pragma unroll
  for (int tm = 0; tm < 4; tm++) {
#pragma unroll
    for (int tn = 0; tn < 4; tn++) {
      const int ng = n0 + wn + tn * 16 + lrow;
      const int h = ng >> 6, d = ng & 63;
      if (mode == 2) {
        // Vt[d][s]: each lane owns 4 consecutive s at fixed d -> one u16x4
        // (8B) store; 16x fewer L2 line-transactions than 64 scalar stores.
        const int mg = m0 + wm + tm * 16 + lq * 4;
        const int b = mg >> 11, s = mg & 2047;
        u16x4 o = { f2bf(acc[tm][tn][0]), f2bf(acc[tm][tn][1]),
                    f2bf(acc[tm][tn][2]), f2bf(acc[tm][tn][3]) };
        *(u16x4*)&Vt[((size_t)(b * 16 + h) * 64 + d) * 2048 + s] = o;
      } else {
#pragma unroll
        for (int i = 0; i < 4; i++) {
          const int mg = m0 + wm + tm * 16 + lq * 4 + i;
          const int b = mg >> 11, s = mg & 2047;
          const float v = acc[tm][tn][i];
          if (mode == 0)
            Qh[((size_t)(b * 16 + h) * 2048 + s) * 64 + d] = f2bf(v * 0.125f);
          else
            Kh[((size_t)(b * 16 + h) * 2048 + s) * 64 + d] = f2bf(v);
        }
      }
    }
  }
}

// ---------------- output projection ----------------
__global__ __launch_bounds__(256) void gemm_proj_kernel(
    const u16* __restrict__ xatt, const u16* __restrict__ pwb,
    const float* __restrict__ bias, float* __restrict__ out) {
  __shared__ u16 a_s[128*32], b_s[128*32];
  const int m0 = blockIdx.y * 128, n0 = blockIdx.x * 128;
  const int t = threadIdx.x;
  f32x4 acc[4][4];
  const f32x4 Z = {0.f, 0.f, 0.f, 0.f};
#pragma unroll
  for (int i = 0; i < 4; i++)
#pragma unroll
    for (int j = 0; j < 4; j++) acc[i][j] = Z;

  gemm_core_1024(xatt, pwb, m0, n0, t, a_s, b_s, acc);

  const int lane = t & 63, w = t >> 6;
  const int wm = (w & 1) * 64, wn = (w >> 1) * 64;
  const int lrow = lane & 15, lq = lane >> 4;
#pragma unroll
  for (int tn = 0; tn < 4; tn++) {
    const int ng = n0 + wn + tn * 16 + lrow;
    const float bv = bias[ng];
#pragma unroll
    for (int tm = 0; tm < 4; tm++) {
#pragma unroll
      for (int i = 0; i < 4; i++) {
        const int mg = m0 + wm + tm * 16 + lq * 4 + i;
        out[(size_t)mg * 1024 + ng] = acc[tm][tn][i] + bv;
      }
    }
  }
}

// ---------------- fused causal attention (Round-3 proven version) ----------------
// Block = pair of q-tiles {p*64, (31-p)*64} x one bh. Uniform 33 chunk-iters.
// K/V in XOR-swizzled LDS (pre-swizzled global source, swizzled read).
// Pass 2 per chunk: QK -> P (fp32 LDS round-trip, coalesced 128B-line attn
// stores, pf rebuilt via f2bf) -> PV.  Chunks strictly sequential;
// __launch_bounds__(256,2) -> 2 blocks/CU.

static __device__ __forceinline__ void qk_tile(const s16x8 qf[2], const s16x8 kf[4][2],
                                               f32x4 sacc[4]) {
  const f32x4 Z = {0.f, 0.f, 0.f, 0.f};
#pragma unroll
  for (int tn = 0; tn < 4; tn++) {
    sacc[tn] = Z;
#pragma unroll
    for (int kq = 0; kq < 2; kq++)
      sacc[tn] = mfma_bf16(qf[kq], kf[tn][kq], sacc[tn]);
  }
}

static __device__ __forceinline__ void expsum_tile(const f32x4 sacc[4], bool diag,
                                                   int lrow, int rbase, float l_acc[4]) {
  float part[4] = {0.f, 0.f, 0.f, 0.f};
#pragma unroll
  for (int tn = 0; tn < 4; tn++)
#pragma unroll
    for (int i = 0; i < 4; i++) {
      const bool ok = !diag || (tn * 16 + lrow <= rbase + i);
      part[i] += ok ? __expf(sacc[tn][i]) : 0.f;
    }
#pragma unroll
  for (int i = 0; i < 4; i++) {
    float s = part[i];
    s += __shfl_xor(s, 1, 16);
    s += __shfl_xor(s, 2, 16);
    s += __shfl_xor(s, 4, 16);
    s += __shfl_xor(s, 8, 16);
    l_acc[i] += s;
  }
}

// P phase: compute pv, stage to fp32 LDS tile (stride 68), emit 4 full-128B-
// line dwordx4 attn stores, rebuild pf via f2bf (bit-identical).
static __device__ __forceinline__ void p_phase(const f32x4 sacc[4], bool diag,
                                               int lane, int lrow, int lq, int w,
                                               const float invl[4], float* pw,
                                               float* __restrict__ gb, s16x8 pf[2]) {
#pragma unroll
  for (int tn = 0; tn < 4; tn++)
#pragma unroll
    for (int i = 0; i < 4; i++) {
      const int rl = lq * 4 + i;
      const bool ok = !diag || (tn * 16 + lrow <= w * 16 + rl);
      const float pv = ok ? __expf(sacc[tn][i]) * invl[i] : 0.f;
      pw[rl * 68 + tn * 16 + lrow] = pv;
    }
  const int rr = lane >> 3, c8 = (lane & 7) * 4;
#pragma unroll
  for (int j = 0; j < 2; j++)
#pragma unroll
    for (int m = 0; m < 2; m++) {
      f32x4 vv = *(const f32x4*)&pw[(rr + 8 * j) * 68 + m * 32 + c8];
      *(f32x4*)&gb[(size_t)(rr + 8 * j) * 2048 + m * 32 + c8] = vv;
    }
#pragma unroll
  for (int kq = 0; kq < 2; kq++) {
    f32x4 lo = *(const f32x4*)&pw[lrow * 68 + kq * 32 + lq * 8];
    f32x4 hi = *(const f32x4*)&pw[lrow * 68 + kq * 32 + lq * 8 + 4];
    s16x8 r;
    r[0] = (short)f2bf(lo.x); r[1] = (short)f2bf(lo.y);
    r[2] = (short)f2bf(lo.z); r[3] = (short)f2bf(lo.w);
    r[4] = (short)f2bf(hi.x); r[5] = (short)f2bf(hi.y);
    r[6] = (short)f2bf(hi.z); r[7] = (short)f2bf(hi.w);
    pf[kq] = r;
  }
}

__global__ __launch_bounds__(256, 2) void attn_kernel(
    const u16* __restrict__ Qh, const u16* __restrict__ Kh, const u16* __restrict__ Vt,
    float* __restrict__ attn, u16* __restrict__ xatt, const int* __restrict__ use_mask_p) {
  // 49.4 KB LDS: K dbuf (16K) | Q-then-V dbuf (16K) | per-wave fp32 P tile (17K)
  __shared__ u16 smem[8192 + 8192];
  __shared__ float p32[4][16 * 68];
  u16* k_s = smem;            // [2][64*64]
  u16* vq  = smem + 8192;     // Q chunks A,B at start; later V double buffer

  const int bh = blockIdx.y;
  const int p  = blockIdx.x;            // pair index 0..15
  const int t = threadIdx.x;
  const int lane = t & 63, w = t >> 6;
  const int lrow = lane & 15, lq = lane >> 4;
  const int use_mask = *use_mask_p;

  const int q0[2] = { p * 64, (31 - p) * 64 };
  const int Tc[2] = { use_mask ? p : 31, use_mask ? 31 - p : 31 };
  const int Tmax  = Tc[1];              // >= Tc[0] always

  const int rs  = t >> 3;                         // staging row 0..31
  const int csw = (((t & 7) ^ (rs & 7)) * 8);     // pre-swizzled source col (elems)
  const int sk  = (lrow & 7) << 3;                // read-side swizzle key (elems)

  const u16* kg = Kh + (size_t)bh * (2048 * 64);
  const u16* vg = Vt + (size_t)bh * (64 * 2048);

  // ---- prologue: stage Q (both chunks) into vq, K[0] into k_s[0] ----
  {
    const u16* qgA = Qh + ((size_t)bh * 2048 + q0[0]) * 64;
    const u16* qgB = Qh + ((size_t)bh * 2048 + q0[1]) * 64;
    gll16(qgA + (size_t)rs * 64 + csw,        &vq[t * 8]);
    gll16(qgA + (size_t)(rs + 32) * 64 + csw, &vq[(t + 256) * 8]);
    gll16(qgB + (size_t)rs * 64 + csw,        &vq[4096 + t * 8]);
    gll16(qgB + (size_t)(rs + 32) * 64 + csw, &vq[4096 + (t + 256) * 8]);
    gll16(kg + (size_t)rs * 64 + csw,         &k_s[t * 8]);
    gll16(kg + (size_t)(rs + 32) * 64 + csw,  &k_s[(t + 256) * 8]);
  }
  __syncthreads();

  s16x8 qf[2][2];
  const int qrow = w * 16 + lrow;
#pragma unroll
  for (int kq = 0; kq < 2; kq++) {
    qf[0][kq] = *(const s16x8*)&vq[qrow * 64 + ((kq * 32 + lq * 8) ^ sk)];
    qf[1][kq] = *(const s16x8*)&vq[4096 + qrow * 64 + ((kq * 32 + lq * 8) ^ sk)];
  }

  const int rbase = w * 16 + lq * 4;

  // ---- pass 1: row sums l (K double-buffered, one barrier/iter) ----
  float l_acc[2][4];
#pragma unroll
  for (int c = 0; c < 2; c++)
#pragma unroll
    for (int i = 0; i < 4; i++) l_acc[c][i] = 0.f;

  for (int tt = 0; tt <= Tmax; tt++) {
    const int cur = tt & 1;
    if (tt < Tmax) {
      gll16(kg + (size_t)((tt + 1) * 64 + rs) * 64 + csw,      &k_s[(cur ^ 1) * 4096 + t * 8]);
      gll16(kg + (size_t)((tt + 1) * 64 + rs + 32) * 64 + csw, &k_s[(cur ^ 1) * 4096 + (t + 256) * 8]);
    }
    s16x8 kf[4][2];
#pragma unroll
    for (int tn = 0; tn < 4; tn++)
#pragma unroll
      for (int kq = 0; kq < 2; kq++)
        kf[tn][kq] = *(const s16x8*)&k_s[cur * 4096 + (tn * 16 + lrow) * 64 + ((kq * 32 + lq * 8) ^ sk)];
    f32x4 sacc[4];
    __builtin_amdgcn_s_setprio(1);
    qk_tile(qf[1], kf, sacc);
    __builtin_amdgcn_s_setprio(0);
    expsum_tile(sacc, use_mask && (tt == Tc[1]), lrow, rbase, l_acc[1]);
    if (tt <= Tc[0]) {
      __builtin_amdgcn_s_setprio(1);
      qk_tile(qf[0], kf, sacc);
      __builtin_amdgcn_s_setprio(0);
      expsum_tile(sacc, use_mask && (tt == Tc[0]), lrow, rbase, l_acc[0]);
    }
    __syncthreads();
  }

  float inv_l[2][4];
#pragma unroll
  for (int c = 0; c < 2; c++)
#pragma unroll
    for (int i = 0; i < 4; i++) inv_l[c][i] = 1.0f / l_acc[c][i];

  // ---- pass 2: P write + O = P@V (K and V double-buffered) ----
  f32x4 oacc[2][4];
  const f32x4 Z = {0.f, 0.f, 0.f, 0.f};
#pragma unroll
  for (int c = 0; c < 2; c++)
#pragma unroll
    for (int i = 0; i < 4; i++) oacc[c][i] = Z;

  // stage K[0], V[0] (q in vq is dead: qf lives in registers)
  gll16(kg + (size_t)rs * 64 + csw,          &k_s[t * 8]);
  gll16(kg + (size_t)(rs + 32) * 64 + csw,   &k_s[(t + 256) * 8]);
  gll16(vg + (size_t)rs * 2048 + csw,        &vq[t * 8]);
  gll16(vg + (size_t)(rs + 32) * 2048 + csw, &vq[(t + 256) * 8]);
  __syncthreads();

  float* pw = &p32[w][0];

  for (int tt = 0; tt <= Tmax; tt++) {
    const int cur = tt & 1;
    if (tt < Tmax) {
      gll16(kg + (size_t)((tt + 1) * 64 + rs) * 64 + csw,        &k_s[(cur ^ 1) * 4096 + t * 8]);
      gll16(kg + (size_t)((tt + 1) * 64 + rs + 32) * 64 + csw,   &k_s[(cur ^ 1) * 4096 + (t + 256) * 8]);
      gll16(vg + (size_t)rs * 2048 + (tt + 1) * 64 + csw,        &vq[(cur ^ 1) * 4096 + t * 8]);
      gll16(vg + (size_t)(rs + 32) * 2048 + (tt + 1) * 64 + csw, &vq[(cur ^ 1) * 4096 + (t + 256) * 8]);
    }
    const bool act0 = (tt <= Tc[0]);
    s16x8 kf[4][2];
#pragma unroll
    for (int tn = 0; tn < 4; tn++)
#pragma unroll
      for (int kq = 0; kq < 2; kq++)
        kf[tn][kq] = *(const s16x8*)&k_s[cur * 4096 + (tn * 16 + lrow) * 64 + ((kq * 32 + lq * 8) ^ sk)];
    s16x8 vf[4][2];
#pragma unroll
    for (int td = 0; td < 4; td++)
#pragma unroll
      for (int kq = 0; kq < 2; kq++)
        vf[td][kq] = *(const s16x8*)&vq[cur * 4096 + (td * 16 + lrow) * 64 + ((kq * 32 + lq * 8) ^ sk)];

    // ---- chunk 1 (always active) ----
    {
      f32x4 sacc[4];
      __builtin_amdgcn_s_setprio(1);
      qk_tile(qf[1], kf, sacc);
      __builtin_amdgcn_s_setprio(0);
      s16x8 pf[2];
      float* gb = attn + ((size_t)(bh * 2048 + q0[1] + w * 16)) * 2048 + tt * 64;
      p_phase(sacc, use_mask && (tt == Tc[1]), lane, lrow, lq, w, inv_l[1], pw, gb, pf);
      __builtin_amdgcn_s_setprio(1);
#pragma unroll
      for (int td = 0; td < 4; td++)
#pragma unroll
        for (int kq = 0; kq < 2; kq++)
          oacc[1][td] = mfma_bf16(pf[kq], vf[td][kq], oacc[1][td]);
      __builtin_amdgcn_s_setprio(0);
    }
    // ---- chunk 0 (active while tt <= Tc[0]) ----
    if (act0) {
      f32x4 sacc[4];
      __builtin_amdgcn_s_setprio(1);
      qk_tile(qf[0], kf, sacc);
      __builtin_amdgcn_s_setprio(0);
      s16x8 pf[2];
      float* gb = attn + ((size_t)(bh * 2048 + q0[0] + w * 16)) * 2048 + tt * 64;
      p_phase(sacc, use_mask && (tt == Tc[0]), lane, lrow, lq, w, inv_l[0], pw, gb, pf);
      __builtin_amdgcn_s_setprio(1);
#pragma unroll
      for (int td = 0; td < 4; td++)
#pragma unroll
        for (int kq = 0; kq < 2; kq++)
          oacc[0][td] = mfma_bf16(pf[kq], vf[td][kq], oacc[0][td]);
      __builtin_amdgcn_s_setprio(0);
    }
    __syncthreads();
  }

  // ---- O -> xatt (B,N,C) bf16, both chunks ----
  const int b = bh >> 4, h = bh & 15;
#pragma unroll
  for (int c = 0; c < 2; c++)
#pragma unroll
    for (int td = 0; td < 4; td++)
#pragma unroll
      for (int i = 0; i < 4; i++) {
        const int row = q0[c] + w * 16 + lq * 4 + i;
        xatt[((size_t)(b * 2048 + row)) * 1024 + h * 64 + td * 16 + lrow] = f2bf(oacc[c][td][i]);
      }

  // ---- zero-fill masked upper region: full 128B lines (8 lanes x 16B / row) ----
  if (use_mask) {
    const f32x4 Z4 = {0.f, 0.f, 0.f, 0.f};
    const int rr = t >> 3;          // 0..31
    const int c8 = (t & 7) * 4;     // float offset within 32-float chunk
#pragma unroll
    for (int c = 0; c < 2; c++) {
      const int zc0 = q0[c] + 64;
      if (zc0 < 2048) {
        const int n32 = (2048 - zc0) >> 5;   // 32-float (128B) chunks per row
        float* zb = attn + ((size_t)bh * 2048 + q0[c]) * 2048 + zc0;
        for (int j = 0; j < n32; j++) {
          *(f32x4*)&zb[(size_t)rr * 2048 + j * 32 + c8] = Z4;
          *(f32x4*)&zb[(size_t)(rr + 32) * 2048 + j * 32 + c8] = Z4;
        }
      }
    }
  }
}

extern "C" void kernel_launch(void* const* d_in, const int* in_sizes, int n_in,
                              void* d_out, int out_size, void* d_ws, size_t ws_size,
                              hipStream_t stream) {
  const float* q      = (const float*)d_in[0];
  const float* k      = (const float*)d_in[1];
  const float* v      = (const float*)d_in[2];
  const float* qkv_w  = (const float*)d_in[3];
  const float* proj_w = (const float*)d_in[4];
  const float* proj_b = (const float*)d_in[5];
  const int*   use_mask = (const int*)d_in[6];

  const size_t MB = 1024 * 1024;
  char* ws = (char*)d_ws;
  u16* qb  = (u16*)(ws + 0 * MB);   // 8 MB (reused as xatt after QKV gemm)
  u16* kb  = (u16*)(ws + 8 * MB);   // 8 MB
  u16* vb  = (u16*)(ws + 16 * MB);  // 8 MB
  u16* wb  = (u16*)(ws + 24 * MB);  // 6 MB
  u16* pwb = (u16*)(ws + 30 * MB);  // 2 MB
  u16* Qh  = (u16*)(ws + 32 * MB);  // 8 MB
  u16* Kh  = (u16*)(ws + 40 * MB);  // 8 MB
  u16* Vt  = (u16*)(ws + 48 * MB);  // 8 MB
  u16* xat = qb;                    // qb dead after gemm_qkv; reuse

  float* out_x    = (float*)d_out;
  float* out_attn = out_x + (size_t)2 * 2048 * 1024;

  cast_all_kernel<<<16384, 256, 0, stream>>>(q, k, v, qkv_w, proj_w, qb, kb, vb, wb, pwb);

  gemm_qkv_kernel<<<dim3(8, 32, 3), 256, 0, stream>>>(qb, kb, vb, wb, Qh, Kh, Vt);
  attn_kernel<<<dim3(16, 32), 256, 0, stream>>>(Qh, Kh, Vt, out_attn, xat, use_mask);
  gemm_proj_kernel<<<dim3(8, 32), 256, 0, stream>>>(xat, pwb, proj_b, out_x);
}

// Round 7
// 713.496 us; speedup vs baseline: 1.1085x; 1.0155x over previous
//
#include <hip/hip_runtime.h>

// Attention_2035814498461 on MI355X (gfx950).
// B=2 N=2048 C=1024 H=16 hd=64, causal mask, outputs (x fp32, attn fp32).
// Round-7 (vs R6 724us / R3 715us, same family): single isolated change —
// attn pass-1 cross-lane reduction DEFERRED out of the tile loop.
// Was: 16 __shfl_xor (ds_permute, 1KB each through the 128B/cy LDS pipe) per
// chunk-iter ≈ 800 LDS-pipe instrs/wave. Now: per-lane fp32 accumulation in
// the loop, ONE 16-lane shuffle-reduce at the end (32 shuffles total).
// Linear-sum reordering only; rounding diff ~1e-6 vs 1.5e-2 tolerance.
// Everything else identical to R6 (LDS-staged dbuf attn, pairing, swizzle,
// coalesced P/zero stores, Vt u16x4, merged casts).

typedef unsigned short u16;
typedef unsigned int u32;
typedef __attribute__((ext_vector_type(8))) short s16x8;
typedef __attribute__((ext_vector_type(4))) float f32x4;
typedef __attribute__((ext_vector_type(4))) u16 u16x4;

#define AS1 __attribute__((address_space(1)))
#define AS3 __attribute__((address_space(3)))

static __device__ __forceinline__ u16 f2bf(float f) {
  u32 u = __builtin_bit_cast(u32, f);
  u = (u + 0x7fffu + ((u >> 16) & 1u)) >> 16;
  return (u16)u;
}

static __device__ __forceinline__ void gll16(const u16* g, u16* l) {
  // async global->LDS, 16B per lane; LDS dest must be wave-uniform base + lane*16
  __builtin_amdgcn_global_load_lds((const AS1 u32*)g, (AS3 u32*)l, 16, 0, 0);
}

static __device__ __forceinline__ f32x4 mfma_bf16(s16x8 a, s16x8 b, f32x4 c) {
  return __builtin_amdgcn_mfma_f32_16x16x32_bf16(a, b, c, 0, 0, 0);
}

// ---------------- merged cast fp32 -> bf16 ----------------
__global__ __launch_bounds__(256) void cast_all_kernel(
    const float* __restrict__ q, const float* __restrict__ k, const float* __restrict__ v,
    const float* __restrict__ qkv_w, const float* __restrict__ proj_w,
    u16* __restrict__ qb, u16* __restrict__ kb, u16* __restrict__ vb,
    u16* __restrict__ wb, u16* __restrict__ pwb) {
  int i = blockIdx.x * 256 + threadIdx.x;
  const float* src; u16* dst; int off;
  if (i < 1048576)       { src = q;      dst = qb;  off = i; }
  else if (i < 2097152)  { src = k;      dst = kb;  off = i - 1048576; }
  else if (i < 3145728)  { src = v;      dst = vb;  off = i - 2097152; }
  else if (i < 3932160)  { src = qkv_w;  dst = wb;  off = i - 3145728; }
  else if (i < 4194304)  { src = proj_w; dst = pwb; off = i - 3932160; }
  else return;
  f32x4 vv = ((const f32x4*)src)[off];
  u16x4 o = { f2bf(vv.x), f2bf(vv.y), f2bf(vv.z), f2bf(vv.w) };
  ((u16x4*)dst)[off] = o;
}

// ---------------- shared 128x128 BT-GEMM core, K=1024 ----------------
static __device__ __forceinline__ void gemm_core_1024(
    const u16* __restrict__ A, const u16* __restrict__ Bm,
    int m0, int n0, int t, u16* a_s, u16* b_s, f32x4 acc[4][4]) {
  const int lane = t & 63;
  const int w = t >> 6;
  const int wm = (w & 1) * 64, wn = (w >> 1) * 64;
  const int lrow = lane & 15, lq = lane >> 4;
  const int r0 = t >> 2;          // staging row 0..63
  const int c0 = (t & 3) * 8;     // staging col (elements)

  for (int kt = 0; kt < 1024; kt += 32) {
    __syncthreads();
    gll16(A  + (size_t)(m0 + r0)      * 1024 + kt + c0, &a_s[(size_t)t * 8]);
    gll16(A  + (size_t)(m0 + r0 + 64) * 1024 + kt + c0, &a_s[(size_t)(t + 256) * 8]);
    gll16(Bm + (size_t)(n0 + r0)      * 1024 + kt + c0, &b_s[(size_t)t * 8]);
    gll16(Bm + (size_t)(n0 + r0 + 64) * 1024 + kt + c0, &b_s[(size_t)(t + 256) * 8]);
    __syncthreads();
    s16x8 af[4], bfr[4];
#pragma unroll
    for (int x = 0; x < 4; x++) af[x]  = *(const s16x8*)&a_s[(wm + x*16 + lrow)*32 + lq*8];
#pragma unroll
    for (int x = 0; x < 4; x++) bfr[x] = *(const s16x8*)&b_s[(wn + x*16 + lrow)*32 + lq*8];
#pragma unroll
    for (int tm = 0; tm < 4; tm++)
#pragma unroll
      for (int tn = 0; tn < 4; tn++)
        acc[tm][tn] = mfma_bf16(af[tm], bfr[tn], acc[tm][tn]);
  }
}

// ---------------- QKV projection (Vt store coalesced) ----------------
__global__ __launch_bounds__(256) void gemm_qkv_kernel(
    const u16* __restrict__ qb, const u16* __restrict__ kb, const u16* __restrict__ vb,
    const u16* __restrict__ wb, u16* __restrict__ Qh, u16* __restrict__ Kh,
    u16* __restrict__ Vt) {
  __shared__ u16 a_s[128*32], b_s[128*32];
  const int mode = blockIdx.z;
  const u16* A = (mode == 0) ? qb : (mode == 1) ? kb : vb;
  const u16* Bm = wb + (size_t)mode * (1024 * 1024);
  const int m0 = blockIdx.y * 128, n0 = blockIdx.x * 128;
  const int t = threadIdx.x;
  f32x4 acc[4][4];
  const f32x4 Z = {0.f, 0.f, 0.f, 0.f};
#pragma unroll
  for (int i = 0; i < 4; i++)
#pragma unroll
    for (int j = 0; j < 4; j++) acc[i][j] = Z;

  gemm_core_1024(A, Bm, m0, n0, t, a_s, b_s, acc);

  const int lane = t & 63, w = t >> 6;
  const int wm = (w & 1) * 64, wn = (w >> 1) * 64;
  const int lrow = lane & 15, lq = lane >> 4;
#pragma unroll
  for (int tm = 0; tm < 4; tm++) {
#pragma unroll
    for (int tn = 0; tn < 4; tn++) {
      const int ng = n0 + wn + tn * 16 + lrow;
      const int h = ng >> 6, d = ng & 63;
      if (mode == 2) {
        const int mg = m0 + wm + tm * 16 + lq * 4;
        const int b = mg >> 11, s = mg & 2047;
        u16x4 o = { f2bf(acc[tm][tn][0]), f2bf(acc[tm][tn][1]),
                    f2bf(acc[tm][tn][2]), f2bf(acc[tm][tn][3]) };
        *(u16x4*)&Vt[((size_t)(b * 16 + h) * 64 + d) * 2048 + s] = o;
      } else {
#pragma unroll
        for (int i = 0; i < 4; i++) {
          const int mg = m0 + wm + tm * 16 + lq * 4 + i;
          const int b = mg >> 11, s = mg & 2047;
          const float v = acc[tm][tn][i];
          if (mode == 0)
            Qh[((size_t)(b * 16 + h) * 2048 + s) * 64 + d] = f2bf(v * 0.125f);
          else
            Kh[((size_t)(b * 16 + h) * 2048 + s) * 64 + d] = f2bf(v);
        }
      }
    }
  }
}

// ---------------- output projection ----------------
__global__ __launch_bounds__(256) void gemm_proj_kernel(
    const u16* __restrict__ xatt, const u16* __restrict__ pwb,
    const float* __restrict__ bias, float* __restrict__ out) {
  __shared__ u16 a_s[128*32], b_s[128*32];
  const int m0 = blockIdx.y * 128, n0 = blockIdx.x * 128;
  const int t = threadIdx.x;
  f32x4 acc[4][4];
  const f32x4 Z = {0.f, 0.f, 0.f, 0.f};
#pragma unroll
  for (int i = 0; i < 4; i++)
#pragma unroll
    for (int j = 0; j < 4; j++) acc[i][j] = Z;

  gemm_core_1024(xatt, pwb, m0, n0, t, a_s, b_s, acc);

  const int lane = t & 63, w = t >> 6;
  const int wm = (w & 1) * 64, wn = (w >> 1) * 64;
  const int lrow = lane & 15, lq = lane >> 4;
#pragma unroll
  for (int tn = 0; tn < 4; tn++) {
    const int ng = n0 + wn + tn * 16 + lrow;
    const float bv = bias[ng];
#pragma unroll
    for (int tm = 0; tm < 4; tm++) {
#pragma unroll
      for (int i = 0; i < 4; i++) {
        const int mg = m0 + wm + tm * 16 + lq * 4 + i;
        out[(size_t)mg * 1024 + ng] = acc[tm][tn][i] + bv;
      }
    }
  }
}

// ---------------- fused causal attention ----------------
// Block = pair of q-tiles {p*64, (31-p)*64} x one bh. Uniform 33 chunk-iters.
// K/V in XOR-swizzled LDS (pre-swizzled global source, swizzled read).
// Pass 1: per-lane exp-accumulation, cross-lane reduce DEFERRED to after the
// loop (this round's change). Pass 2 per chunk: QK -> P (fp32 LDS round-trip,
// 128B-line attn stores, pf via f2bf) -> PV. __launch_bounds__(256,2).

static __device__ __forceinline__ void qk_tile(const s16x8 qf[2], const s16x8 kf[4][2],
                                               f32x4 sacc[4]) {
  const f32x4 Z = {0.f, 0.f, 0.f, 0.f};
#pragma unroll
  for (int tn = 0; tn < 4; tn++) {
    sacc[tn] = Z;
#pragma unroll
    for (int kq = 0; kq < 2; kq++)
      sacc[tn] = mfma_bf16(qf[kq], kf[tn][kq], sacc[tn]);
  }
}

// per-lane exp accumulation, NO cross-lane traffic (reduce deferred)
static __device__ __forceinline__ void expacc_tile(const f32x4 sacc[4], bool diag,
                                                   int lrow, int rbase, float part[4]) {
#pragma unroll
  for (int tn = 0; tn < 4; tn++)
#pragma unroll
    for (int i = 0; i < 4; i++) {
      const bool ok = !diag || (tn * 16 + lrow <= rbase + i);
      part[i] += ok ? __expf(sacc[tn][i]) : 0.f;
    }
}

// P phase: compute pv, stage to fp32 LDS tile (stride 68), emit 4 full-128B-
// line dwordx4 attn stores, rebuild pf via f2bf (bit-identical).
static __device__ __forceinline__ void p_phase(const f32x4 sacc[4], bool diag,
                                               int lane, int lrow, int lq, int w,
                                               const float invl[4], float* pw,
                                               float* __restrict__ gb, s16x8 pf[2]) {
#pragma unroll
  for (int tn = 0; tn < 4; tn++)
#pragma unroll
    for (int i = 0; i < 4; i++) {
      const int rl = lq * 4 + i;
      const bool ok = !diag || (tn * 16 + lrow <= w * 16 + rl);
      const float pv = ok ? __expf(sacc[tn][i]) * invl[i] : 0.f;
      pw[rl * 68 + tn * 16 + lrow] = pv;
    }
  const int rr = lane >> 3, c8 = (lane & 7) * 4;
#pragma unroll
  for (int j = 0; j < 2; j++)
#pragma unroll
    for (int m = 0; m < 2; m++) {
      f32x4 vv = *(const f32x4*)&pw[(rr + 8 * j) * 68 + m * 32 + c8];
      *(f32x4*)&gb[(size_t)(rr + 8 * j) * 2048 + m * 32 + c8] = vv;
    }
#pragma unroll
  for (int kq = 0; kq < 2; kq++) {
    f32x4 lo = *(const f32x4*)&pw[lrow * 68 + kq * 32 + lq * 8];
    f32x4 hi = *(const f32x4*)&pw[lrow * 68 + kq * 32 + lq * 8 + 4];
    s16x8 r;
    r[0] = (short)f2bf(lo.x); r[1] = (short)f2bf(lo.y);
    r[2] = (short)f2bf(lo.z); r[3] = (short)f2bf(lo.w);
    r[4] = (short)f2bf(hi.x); r[5] = (short)f2bf(hi.y);
    r[6] = (short)f2bf(hi.z); r[7] = (short)f2bf(hi.w);
    pf[kq] = r;
  }
}

__global__ __launch_bounds__(256, 2) void attn_kernel(
    const u16* __restrict__ Qh, const u16* __restrict__ Kh, const u16* __restrict__ Vt,
    float* __restrict__ attn, u16* __restrict__ xatt, const int* __restrict__ use_mask_p) {
  // 49.4 KB LDS: K dbuf (16K) | Q-then-V dbuf (16K) | per-wave fp32 P tile (17K)
  __shared__ u16 smem[8192 + 8192];
  __shared__ float p32[4][16 * 68];
  u16* k_s = smem;            // [2][64*64]
  u16* vq  = smem + 8192;     // Q chunks A,B at start; later V double buffer

  const int bh = blockIdx.y;
  const int p  = blockIdx.x;            // pair index 0..15
  const int t = threadIdx.x;
  const int lane = t & 63, w = t >> 6;
  const int lrow = lane & 15, lq = lane >> 4;
  const int use_mask = *use_mask_p;

  const int q0[2] = { p * 64, (31 - p) * 64 };
  const int Tc[2] = { use_mask ? p : 31, use_mask ? 31 - p : 31 };
  const int Tmax  = Tc[1];              // >= Tc[0] always

  const int rs  = t >> 3;                         // staging row 0..31
  const int csw = (((t & 7) ^ (rs & 7)) * 8);     // pre-swizzled source col (elems)
  const int sk  = (lrow & 7) << 3;                // read-side swizzle key (elems)

  const u16* kg = Kh + (size_t)bh * (2048 * 64);
  const u16* vg = Vt + (size_t)bh * (64 * 2048);

  // ---- prologue: stage Q (both chunks) into vq, K[0] into k_s[0] ----
  {
    const u16* qgA = Qh + ((size_t)bh * 2048 + q0[0]) * 64;
    const u16* qgB = Qh + ((size_t)bh * 2048 + q0[1]) * 64;
    gll16(qgA + (size_t)rs * 64 + csw,        &vq[t * 8]);
    gll16(qgA + (size_t)(rs + 32) * 64 + csw, &vq[(t + 256) * 8]);
    gll16(qgB + (size_t)rs * 64 + csw,        &vq[4096 + t * 8]);
    gll16(qgB + (size_t)(rs + 32) * 64 + csw, &vq[4096 + (t + 256) * 8]);
    gll16(kg + (size_t)rs * 64 + csw,         &k_s[t * 8]);
    gll16(kg + (size_t)(rs + 32) * 64 + csw,  &k_s[(t + 256) * 8]);
  }
  __syncthreads();

  s16x8 qf[2][2];
  const int qrow = w * 16 + lrow;
#pragma unroll
  for (int kq = 0; kq < 2; kq++) {
    qf[0][kq] = *(const s16x8*)&vq[qrow * 64 + ((kq * 32 + lq * 8) ^ sk)];
    qf[1][kq] = *(const s16x8*)&vq[4096 + qrow * 64 + ((kq * 32 + lq * 8) ^ sk)];
  }

  const int rbase = w * 16 + lq * 4;

  // ---- pass 1: per-lane exp sums (K double-buffered, one barrier/iter) ----
  float part_acc[2][4];
#pragma unroll
  for (int c = 0; c < 2; c++)
#pragma unroll
    for (int i = 0; i < 4; i++) part_acc[c][i] = 0.f;

  for (int tt = 0; tt <= Tmax; tt++) {
    const int cur = tt & 1;
    if (tt < Tmax) {
      gll16(kg + (size_t)((tt + 1) * 64 + rs) * 64 + csw,      &k_s[(cur ^ 1) * 4096 + t * 8]);
      gll16(kg + (size_t)((tt + 1) * 64 + rs + 32) * 64 + csw, &k_s[(cur ^ 1) * 4096 + (t + 256) * 8]);
    }
    s16x8 kf[4][2];
#pragma unroll
    for (int tn = 0; tn < 4; tn++)
#pragma unroll
      for (int kq = 0; kq < 2; kq++)
        kf[tn][kq] = *(const s16x8*)&k_s[cur * 4096 + (tn * 16 + lrow) * 64 + ((kq * 32 + lq * 8) ^ sk)];
    f32x4 sacc[4];
    __builtin_amdgcn_s_setprio(1);
    qk_tile(qf[1], kf, sacc);
    __builtin_amdgcn_s_setprio(0);
    expacc_tile(sacc, use_mask && (tt == Tc[1]), lrow, rbase, part_acc[1]);
    if (tt <= Tc[0]) {
      __builtin_amdgcn_s_setprio(1);
      qk_tile(qf[0], kf, sacc);
      __builtin_amdgcn_s_setprio(0);
      expacc_tile(sacc, use_mask && (tt == Tc[0]), lrow, rbase, part_acc[0]);
    }
    __syncthreads();
  }

  // ---- deferred cross-lane reduce: one 16-lane tree per (chunk,i) ----
  float inv_l[2][4];
#pragma unroll
  for (int c = 0; c < 2; c++)
#pragma unroll
    for (int i = 0; i < 4; i++) {
      float s = part_acc[c][i];
      s += __shfl_xor(s, 1, 16);
      s += __shfl_xor(s, 2, 16);
      s += __shfl_xor(s, 4, 16);
      s += __shfl_xor(s, 8, 16);
      inv_l[c][i] = 1.0f / s;
    }

  // ---- pass 2: P write + O = P@V (K and V double-buffered) ----
  f32x4 oacc[2][4];
  const f32x4 Z = {0.f, 0.f, 0.f, 0.f};
#pragma unroll
  for (int c = 0; c < 2; c++)
#pragma unroll
    for (int i = 0; i < 4; i++) oacc[c][i] = Z;

  // stage K[0], V[0] (q in vq is dead: qf lives in registers)
  gll16(kg + (size_t)rs * 64 + csw,          &k_s[t * 8]);
  gll16(kg + (size_t)(rs + 32) * 64 + csw,   &k_s[(t + 256) * 8]);
  gll16(vg + (size_t)rs * 2048 + csw,        &vq[t * 8]);
  gll16(vg + (size_t)(rs + 32) * 2048 + csw, &vq[(t + 256) * 8]);
  __syncthreads();

  float* pw = &p32[w][0];

  for (int tt = 0; tt <= Tmax; tt++) {
    const int cur = tt & 1;
    if (tt < Tmax) {
      gll16(kg + (size_t)((tt + 1) * 64 + rs) * 64 + csw,        &k_s[(cur ^ 1) * 4096 + t * 8]);
      gll16(kg + (size_t)((tt + 1) * 64 + rs + 32) * 64 + csw,   &k_s[(cur ^ 1) * 4096 + (t + 256) * 8]);
      gll16(vg + (size_t)rs * 2048 + (tt + 1) * 64 + csw,        &vq[(cur ^ 1) * 4096 + t * 8]);
      gll16(vg + (size_t)(rs + 32) * 2048 + (tt + 1) * 64 + csw, &vq[(cur ^ 1) * 4096 + (t + 256) * 8]);
    }
    const bool act0 = (tt <= Tc[0]);
    s16x8 kf[4][2];
#pragma unroll
    for (int tn = 0; tn < 4; tn++)
#pragma unroll
      for (int kq = 0; kq < 2; kq++)
        kf[tn][kq] = *(const s16x8*)&k_s[cur * 4096 + (tn * 16 + lrow) * 64 + ((kq * 32 + lq * 8) ^ sk)];
    s16x8 vf[4][2];
#pragma unroll
    for (int td = 0; td < 4; td++)
#pragma unroll
      for (int kq = 0; kq < 2; kq++)
        vf[td][kq] = *(const s16x8*)&vq[cur * 4096 + (td * 16 + lrow) * 64 + ((kq * 32 + lq * 8) ^ sk)];

    // ---- chunk 1 (always active) ----
    {
      f32x4 sacc[4];
      __builtin_amdgcn_s_setprio(1);
      qk_tile(qf[1], kf, sacc);
      __builtin_amdgcn_s_setprio(0);
      s16x8 pf[2];
      float* gb = attn + ((size_t)(bh * 2048 + q0[1] + w * 16)) * 2048 + tt * 64;
      p_phase(sacc, use_mask && (tt == Tc[1]), lane, lrow, lq, w, inv_l[1], pw, gb, pf);
      __builtin_amdgcn_s_setprio(1);
#pragma unroll
      for (int td = 0; td < 4; td++)
#pragma unroll
        for (int kq = 0; kq < 2; kq++)
          oacc[1][td] = mfma_bf16(pf[kq], vf[td][kq], oacc[1][td]);
      __builtin_amdgcn_s_setprio(0);
    }
    // ---- chunk 0 (active while tt <= Tc[0]) ----
    if (act0) {
      f32x4 sacc[4];
      __builtin_amdgcn_s_setprio(1);
      qk_tile(qf[0], kf, sacc);
      __builtin_amdgcn_s_setprio(0);
      s16x8 pf[2];
      float* gb = attn + ((size_t)(bh * 2048 + q0[0] + w * 16)) * 2048 + tt * 64;
      p_phase(sacc, use_mask && (tt == Tc[0]), lane, lrow, lq, w, inv_l[0], pw, gb, pf);
      __builtin_amdgcn_s_setprio(1);
#pragma unroll
      for (int td = 0; td < 4; td++)
#pragma unroll
        for (int kq = 0; kq < 2; kq++)
          oacc[0][td] = mfma_bf16(pf[kq], vf[td][kq], oacc[0][td]);
      __builtin_amdgcn_s_setprio(0);
    }
    __syncthreads();
  }

  // ---- O -> xatt (B,N,C) bf16, both chunks ----
  const int b = bh >> 4, h = bh & 15;
#pragma unroll
  for (int c = 0; c < 2; c++)
#pragma unroll
    for (int td = 0; td < 4; td++)
#pragma unroll
      for (int i = 0; i < 4; i++) {
        const int row = q0[c] + w * 16 + lq * 4 + i;
        xatt[((size_t)(b * 2048 + row)) * 1024 + h * 64 + td * 16 + lrow] = f2bf(oacc[c][td][i]);
      }

  // ---- zero-fill masked upper region: full 128B lines (8 lanes x 16B / row) ----
  if (use_mask) {
    const f32x4 Z4 = {0.f, 0.f, 0.f, 0.f};
    const int rr = t >> 3;          // 0..31
    const int c8 = (t & 7) * 4;     // float offset within 32-float chunk
#pragma unroll
    for (int c = 0; c < 2; c++) {
      const int zc0 = q0[c] + 64;
      if (zc0 < 2048) {
        const int n32 = (2048 - zc0) >> 5;   // 32-float (128B) chunks per row
        float* zb = attn + ((size_t)bh * 2048 + q0[c]) * 2048 + zc0;
        for (int j = 0; j < n32; j++) {
          *(f32x4*)&zb[(size_t)rr * 2048 + j * 32 + c8] = Z4;
          *(f32x4*)&zb[(size_t)(rr + 32) * 2048 + j * 32 + c8] = Z4;
        }
      }
    }
  }
}

extern "C" void kernel_launch(void* const* d_in, const int* in_sizes, int n_in,
                              void* d_out, int out_size, void* d_ws, size_t ws_size,
                              hipStream_t stream) {
  const float* q      = (const float*)d_in[0];
  const float* k      = (const float*)d_in[1];
  const float* v      = (const float*)d_in[2];
  const float* qkv_w  = (const float*)d_in[3];
  const float* proj_w = (const float*)d_in[4];
  const float* proj_b = (const float*)d_in[5];
  const int*   use_mask = (const int*)d_in[6];

  const size_t MB = 1024 * 1024;
  char* ws = (char*)d_ws;
  u16* qb  = (u16*)(ws + 0 * MB);   // 8 MB (reused as xatt after QKV gemm)
  u16* kb  = (u16*)(ws + 8 * MB);   // 8 MB
  u16* vb  = (u16*)(ws + 16 * MB);  // 8 MB
  u16* wb  = (u16*)(ws + 24 * MB);  // 6 MB
  u16* pwb = (u16*)(ws + 30 * MB);  // 2 MB
  u16* Qh  = (u16*)(ws + 32 * MB);  // 8 MB
  u16* Kh  = (u16*)(ws + 40 * MB);  // 8 MB
  u16* Vt  = (u16*)(ws + 48 * MB);  // 8 MB
  u16* xat = qb;                    // qb dead after gemm_qkv; reuse

  float* out_x    = (float*)d_out;
  float* out_attn = out_x + (size_t)2 * 2048 * 1024;

  cast_all_kernel<<<16384, 256, 0, stream>>>(q, k, v, qkv_w, proj_w, qb, kb, vb, wb, pwb);

  gemm_qkv_kernel<<<dim3(8, 32, 3), 256, 0, stream>>>(qb, kb, vb, wb, Qh, Kh, Vt);
  attn_kernel<<<dim3(16, 32), 256, 0, stream>>>(Qh, Kh, Vt, out_attn, xat, use_mask);
  gemm_proj_kernel<<<dim3(8, 32), 256, 0, stream>>>(xat, pwb, proj_b, out_x);
}